// Round 5
// baseline (600.532 us; speedup 1.0000x reference)
//
#include <hip/hip_runtime.h>

// Problem constants (from reference): z (64,128,64,64) f32, emb (256,128) f32
#define K_EMB   256
#define C_DIM   128
#define HW      4096            // 64*64
#define NPOS    262144          // 64*HW
#define Q_ELEMS 33554432        // 64*128*64*64
#define IDX_OFF Q_ELEMS         // idx chunk offset in d_out (floats)
#define LOSS_OFF (Q_ELEMS + NPOS)

#define BLKP 128                // positions per block (z tile = 128c x 128p = 64 KB LDS)
#define TK   64                 // codes per wave (k-quarter)
#define NQ   4                  // k-quarters = waves per block
#define PP   2                  // positions per thread (lane, lane+64)

// ws layout (floats): [0,256) enorm, [256] loss accumulator, [512, 512+32768) embT (c*256+k)
#define WS_ENORM 0
#define WS_ACC   256
#define WS_EMBT  512
#define WS_NEED_FULL  ((WS_EMBT + C_DIM * K_EMB) * 4)

// ---------------------------------------------------------------------------
// Kernel A: parallel emb transpose (one block per c), zero loss accum.
// ---------------------------------------------------------------------------
__global__ __launch_bounds__(K_EMB) void vq_transpose(const float* __restrict__ emb,
                                                      float* __restrict__ ws,
                                                      int use_embT) {
    const int c = blockIdx.x, k = threadIdx.x;
    if (use_embT) ws[WS_EMBT + c * K_EMB + k] = emb[k * C_DIM + c];
    if (c == 0 && k == 0) ws[WS_ACC] = 0.f;
}

// ---------------------------------------------------------------------------
// Kernel B: per-code squared norms. Same ascending-c serial fmaf chain as the
// absmax-0 kernels (float4 components consumed in x,y,z,w = ascending c).
// ---------------------------------------------------------------------------
__global__ __launch_bounds__(K_EMB) void vq_enorm(const float* __restrict__ emb,
                                                  float* __restrict__ ws) {
    const int k = threadIdx.x;
    const float4* __restrict__ er = reinterpret_cast<const float4*>(emb + k * C_DIM);
    float s = 0.f;
    #pragma unroll
    for (int j = 0; j < C_DIM / 4; ++j) {
        float4 v = er[j];
        s = fmaf(v.x, v.x, s);
        s = fmaf(v.y, v.y, s);
        s = fmaf(v.z, v.z, s);
        s = fmaf(v.w, v.w, s);
    }
    ws[WS_ENORM + k] = s;
}

// ---------------------------------------------------------------------------
// Kernel 1: LDS-staged split-K VALU GEMM + argmin, 2 positions/thread.
//
// R9 (this round): R8 counters -- FETCH 67 MB (z-restream KILLED), VALUBusy
// stuck 55%, occupancy 37%. Per-wave duty ~18%: per c-step only 130 VALU
// cycles amortize ~600 cycles of scalar-pipe (4x s_load_dwordx16, 256 B of
// wave-uniform embT; SGPR budget too tight to double-buffer) + ds_read
// latency. Fix: 2 positions per thread. Per c-step becomes 2 ds_read + the
// SAME 256 B scalar + 130 fmac -- scalar bytes and staged bytes per FMA
// both halve, and two independent acc chains overlap the s_load shadow.
// Block = 128 positions, 64 KB z tile, 2 blocks/CU (2 waves/SIMD); wave
// duty must only exceed 50% to saturate VALU.
//
// Numerics: bit-identical to the absmax-0 lineage. Each position's znorm /
// dot chains are the same serial ascending-c fmaf chains; d = (znorm -
// 2*acc) + enorm[k]; strict < ascending-k within quarter, ascending-quarter
// combine = global first-min. Loss partials: identical 4096 groups of 64
// consecutive positions, identical lane<->position mapping and shfl tree as
// R8 (wave0 = blk*128+0..63 === old block 2b; wave1 = +64..127 === old
// block 2b+1), same atomic count.
// ---------------------------------------------------------------------------
template <int UT>
__global__ __launch_bounds__(256, 2) void vq_main(const float* __restrict__ z,
                                                  const float* __restrict__ emb,
                                                  const float* __restrict__ ws,
                                                  float* __restrict__ out,
                                                  float* __restrict__ loss_acc) {
    __shared__ float zlds[C_DIM * BLKP];     // [c][p], 64 KB
    __shared__ float sh_best[NQ * BLKP];     // 2 KB
    __shared__ int   sh_bidx[NQ * BLKP];     // 2 KB

    const int t    = threadIdx.x;
    const int lane = t & 63;
    const int kq   = t >> 6;                   // wave id = k-quarter
    const int blk  = blockIdx.x;
    const int b    = blk >> 5;                 // 4096/128 = 32 blocks per image
    const int hw0  = (blk & 31) * BLKP;
    const size_t zoff = (size_t)b * (C_DIM * HW) + hw0;
    const float* __restrict__ zsrc = z + zoff;

    // ---- Stage z tile into LDS (coalesced float4; [c][p] layout) ----
    {
        const float4* __restrict__ zs4 = reinterpret_cast<const float4*>(zsrc);
        float4* __restrict__ zl4 = reinterpret_cast<float4*>(zlds);
        #pragma unroll
        for (int j = 0; j < (C_DIM * BLKP / 4) / 256; ++j) {   // 16 iters
            const int i4 = t + j * 256;
            const int c  = i4 >> 5;            // 32 float4 per c-row (128 floats)
            const int p4 = i4 & 31;
            zl4[i4] = zs4[(size_t)c * (HW / 4) + p4];
        }
    }
    __syncthreads();

    const float* __restrict__ embT  = ws + WS_EMBT;
    const float* __restrict__ enorm = ws + WS_ENORM;

    // kq is uniform across each 64-lane wave: pin k-base in an SGPR so
    // embT/enorm indexing compiles to SCALAR loads (R6 lesson, R7 fix).
    const int kbase = __builtin_amdgcn_readfirstlane(kq * TK);

    float acc0[TK], acc1[TK];
    #pragma unroll
    for (int j = 0; j < TK; ++j) { acc0[j] = 0.f; acc1[j] = 0.f; }
    float znorm0 = 0.f, znorm1 = 0.f;

    #pragma unroll 2
    for (int c = 0; c < C_DIM; ++c) {
        const float z0 = zlds[c * BLKP + lane];        // ds_read2-fusable pair,
        const float z1 = zlds[c * BLKP + lane + 64];   // 2-way bank alias = free
        znorm0 = fmaf(z0, z0, znorm0);                 // same serial chains
        znorm1 = fmaf(z1, z1, znorm1);
        if (UT) {
            const float* __restrict__ ep = embT + c * K_EMB + kbase;  // SGPR-uniform
            #pragma unroll
            for (int j = 0; j < TK; ++j) {
                const float e = ep[j];                 // scalar operand
                acc0[j] = fmaf(z0, e, acc0[j]);        // two independent chains
                acc1[j] = fmaf(z1, e, acc1[j]);
            }
        } else {
            #pragma unroll
            for (int j = 0; j < TK; ++j) {
                const float e = emb[(kbase + j) * C_DIM + c];
                acc0[j] = fmaf(z0, e, acc0[j]);
                acc1[j] = fmaf(z1, e, acc1[j]);
            }
        }
    }

    float best0 = 3.402823466e38f, best1 = 3.402823466e38f;
    int   bidx0 = 0, bidx1 = 0;
    #pragma unroll
    for (int j = 0; j < TK; ++j) {
        const float en = enorm[kbase + j];
        const float d0 = (znorm0 - 2.0f * acc0[j]) + en;
        const float d1 = (znorm1 - 2.0f * acc1[j]) + en;
        if (d0 < best0) { best0 = d0; bidx0 = kbase + j; }  // strict < = first-min
        if (d1 < best1) { best1 = d1; bidx1 = kbase + j; }
    }

    sh_best[kq * BLKP + lane]      = best0;
    sh_bidx[kq * BLKP + lane]      = bidx0;
    sh_best[kq * BLKP + lane + 64] = best1;
    sh_bidx[kq * BLKP + lane + 64] = bidx1;
    __syncthreads();

    if (t < BLKP) {   // waves 0,1: thread t owns position p = t
        const int p = t;
        float bb = sh_best[p];
        int   bi = sh_bidx[p];
        #pragma unroll
        for (int q = 1; q < NQ; ++q) {
            const float bq = sh_best[q * BLKP + p];
            const int   iq = sh_bidx[q * BLKP + p];
            if (bq < bb) { bb = bq; bi = iq; }  // strict <: lower quarter wins ties
        }
        const int fin = bi;
        const int pos = blk * BLKP + p;
        __builtin_nontemporal_store((float)fin, &out[IDX_OFF + pos]);

        // Epilogue: q = z + (e - z), loss += (e - z)^2. z from LDS (bit-copy),
        // e from row-major emb via float4 (bit-equal to embT), ascending-c
        // 128-term chain identical to the absmax-0 lineage.
        float lsum = 0.f;
        float* qp = out + zoff + p;
        const float4* __restrict__ er =
            reinterpret_cast<const float4*>(emb + fin * C_DIM);
        #pragma unroll 4
        for (int j = 0; j < C_DIM / 4; ++j) {
            const float4 ev = er[j];
            const int c0 = j * 4;
            const float z0 = zlds[(c0 + 0) * BLKP + p];
            const float z1 = zlds[(c0 + 1) * BLKP + p];
            const float z2 = zlds[(c0 + 2) * BLKP + p];
            const float z3 = zlds[(c0 + 3) * BLKP + p];
            const float d0 = ev.x - z0, d1 = ev.y - z1;
            const float d2 = ev.z - z2, d3 = ev.w - z3;
            lsum = fmaf(d0, d0, lsum);
            lsum = fmaf(d1, d1, lsum);
            lsum = fmaf(d2, d2, lsum);
            lsum = fmaf(d3, d3, lsum);
            __builtin_nontemporal_store(z0 + d0, &qp[(size_t)(c0 + 0) * HW]);
            __builtin_nontemporal_store(z1 + d1, &qp[(size_t)(c0 + 1) * HW]);
            __builtin_nontemporal_store(z2 + d2, &qp[(size_t)(c0 + 2) * HW]);
            __builtin_nontemporal_store(z3 + d3, &qp[(size_t)(c0 + 3) * HW]);
        }

        // Wave-level reduction: wave0 covers positions blk*128+0..63, wave1
        // covers +64..127 -- the SAME 4096 partial groups as the passing R8.
        #pragma unroll
        for (int off = 32; off > 0; off >>= 1)
            lsum += __shfl_down(lsum, off, 64);
        if (lane == 0) atomicAdd(loss_acc, lsum);
    }
}

// ---------------------------------------------------------------------------
// Kernel 2: finalize the two scalar losses.
// ---------------------------------------------------------------------------
__global__ void vq_finalize(const float* __restrict__ loss_acc,
                            float* __restrict__ out_losses) {
    float S = loss_acc[0];
    float mean = S / (float)Q_ELEMS;
    out_losses[0] = 0.25f * mean;  // commitment_loss
    out_losses[1] = mean;          // codebook_loss
}

extern "C" void kernel_launch(void* const* d_in, const int* in_sizes, int n_in,
                              void* d_out, int out_size, void* d_ws, size_t ws_size,
                              hipStream_t stream) {
    const float* z   = (const float*)d_in[0];
    const float* emb = (const float*)d_in[1];
    float* out = (float*)d_out;
    float* ws  = (float*)d_ws;

    int use_embT = (ws_size >= (size_t)WS_NEED_FULL) ? 1 : 0;

    vq_transpose<<<C_DIM, K_EMB, 0, stream>>>(emb, ws, use_embT);
    vq_enorm<<<1, K_EMB, 0, stream>>>(emb, ws);
    if (use_embT)
        vq_main<1><<<NPOS / BLKP, 256, 0, stream>>>(z, emb, ws, out, ws + WS_ACC);
    else
        vq_main<0><<<NPOS / BLKP, 256, 0, stream>>>(z, emb, ws, out, ws + WS_ACC);
    vq_finalize<<<1, 1, 0, stream>>>(ws + WS_ACC, out + LOSS_OFF);
}

// Round 6
// 391.142 us; speedup vs baseline: 1.5353x; 1.5353x over previous
//
#include <hip/hip_runtime.h>

// Problem constants (from reference): z (64,128,64,64) f32, emb (256,128) f32
#define K_EMB   256
#define C_DIM   128
#define HW      4096            // 64*64
#define NPOS    262144          // 64*HW
#define Q_ELEMS 33554432        // 64*128*64*64
#define IDX_OFF Q_ELEMS         // idx chunk offset in d_out (floats)
#define LOSS_OFF (Q_ELEMS + NPOS)

#define BLKP 64                 // positions per block (z tile = 128c x 64p = 32 KB LDS)
#define TK   32                 // codes per wave (k-octant)
#define NQ   8                  // k-octants = waves per block
#define NTHR 512                // 8 waves

// ws layout (floats): [0,256) enorm, [256] loss accumulator, [512, 512+32768) embT (c*256+k)
#define WS_ENORM 0
#define WS_ACC   256
#define WS_EMBT  512
#define WS_NEED_FULL  ((WS_EMBT + C_DIM * K_EMB) * 4)

// ---------------------------------------------------------------------------
// Kernel A: parallel emb transpose (one block per c), zero loss accum.
// ---------------------------------------------------------------------------
__global__ __launch_bounds__(K_EMB) void vq_transpose(const float* __restrict__ emb,
                                                      float* __restrict__ ws,
                                                      int use_embT) {
    const int c = blockIdx.x, k = threadIdx.x;
    if (use_embT) ws[WS_EMBT + c * K_EMB + k] = emb[k * C_DIM + c];
    if (c == 0 && k == 0) ws[WS_ACC] = 0.f;
}

// ---------------------------------------------------------------------------
// Kernel B: per-code squared norms. Same ascending-c serial fmaf chain as the
// absmax-0 kernels (float4 components consumed in x,y,z,w = ascending c).
// ---------------------------------------------------------------------------
__global__ __launch_bounds__(K_EMB) void vq_enorm(const float* __restrict__ emb,
                                                  float* __restrict__ ws) {
    const int k = threadIdx.x;
    const float4* __restrict__ er = reinterpret_cast<const float4*>(emb + k * C_DIM);
    float s = 0.f;
    #pragma unroll
    for (int j = 0; j < C_DIM / 4; ++j) {
        float4 v = er[j];
        s = fmaf(v.x, v.x, s);
        s = fmaf(v.y, v.y, s);
        s = fmaf(v.z, v.z, s);
        s = fmaf(v.w, v.w, s);
    }
    ws[WS_ENORM + k] = s;
}

// ---------------------------------------------------------------------------
// Kernel 1: LDS-staged 8-way split-K VALU GEMM + argmin.
//
// R10 (this round): R9's PP=2 regressed (257->453us): occupancy halved while
// per-wave duty stayed ~18-19%. Diagnosis: the inner loop mixes SMEM
// (s_load embT) and DS (ds_read z) which SHARE lgkmcnt; SMEM completes
// out-of-order, so every c-step the compiler must s_waitcnt lgkmcnt(0) --
// a full drain of the scalar-load shadow regardless of how much compute
// follows. Per-wave duty is structurally pinned; ILP can't fix a
// serialized drain -- only MORE WAVES can. So: 8-way k-split, 512-thread
// blocks. TK=32 -> per-thread regs ~60 combined (R0's TK=32 measured 28
// arch VGPR, acc parks in AGPRs) -> 8 waves/SIMD feasible; LDS 36 KB -> 4
// blocks/CU x 512 thr = 32 waves/CU (100% cap). 7-8 resident waves x ~18%
// duty oversubscribes the VALU ~1.4x -> busy saturates.
//
// Numerics: bit-identical to the absmax-0 lineage. Each position's znorm /
// dot chains are the same serial ascending-c fmaf chains (znorm redundantly
// per octant, same bits; +3% FLOPs); d = (znorm - 2*acc) + enorm[k];
// strict < ascending-k within octant, ascending-octant strict < combine =
// global first-min. Loss partials: identical 4096 groups of 64 consecutive
// positions, identical wave-0 shfl tree and atomic count as R8/R9.
// ---------------------------------------------------------------------------
template <int UT>
__global__ __launch_bounds__(NTHR, 4) void vq_main(const float* __restrict__ z,
                                                   const float* __restrict__ emb,
                                                   const float* __restrict__ ws,
                                                   float* __restrict__ out,
                                                   float* __restrict__ loss_acc) {
    __shared__ float zlds[C_DIM * BLKP];     // [c][p], 32 KB
    __shared__ float sh_best[NQ * BLKP];     // 2 KB
    __shared__ int   sh_bidx[NQ * BLKP];     // 2 KB

    const int t    = threadIdx.x;
    const int lane = t & 63;                   // position within block
    const int kq   = t >> 6;                   // wave id = k-octant
    const int blk  = blockIdx.x;
    const int b    = blk >> 6;                 // 4096/64 = 64 blocks per image
    const int hw0  = (blk & 63) * BLKP;
    const size_t zoff = (size_t)b * (C_DIM * HW) + hw0;
    const float* __restrict__ zsrc = z + zoff;

    // ---- Stage z tile into LDS (coalesced float4; [c][p] layout) ----
    {
        const float4* __restrict__ zs4 = reinterpret_cast<const float4*>(zsrc);
        float4* __restrict__ zl4 = reinterpret_cast<float4*>(zlds);
        #pragma unroll
        for (int j = 0; j < (C_DIM * BLKP / 4) / NTHR; ++j) {   // 4 iters
            const int i4 = t + j * NTHR;
            const int c  = i4 >> 4;            // 16 float4 per c-row (64 floats)
            const int p4 = i4 & 15;
            zl4[i4] = zs4[(size_t)c * (HW / 4) + p4];
        }
    }
    __syncthreads();

    const float* __restrict__ embT  = ws + WS_EMBT;
    const float* __restrict__ enorm = ws + WS_ENORM;

    // kq is uniform across each 64-lane wave: pin k-base in an SGPR so
    // embT/enorm indexing compiles to SCALAR loads (R6 lesson, R7 fix).
    const int kbase = __builtin_amdgcn_readfirstlane(kq * TK);

    float acc[TK];
    #pragma unroll
    for (int j = 0; j < TK; ++j) acc[j] = 0.f;
    float znorm = 0.f;

    #pragma unroll 2
    for (int c = 0; c < C_DIM; ++c) {
        const float zc = zlds[c * BLKP + lane];   // conflict-free ds_read_b32
        znorm = fmaf(zc, zc, znorm);              // same serial chain as before
        if (UT) {
            const float* __restrict__ ep = embT + c * K_EMB + kbase;  // SGPR-uniform
            #pragma unroll
            for (int j = 0; j < TK; ++j)
                acc[j] = fmaf(zc, ep[j], acc[j]); // v_fmac VGPR x SGPR
        } else {
            #pragma unroll
            for (int j = 0; j < TK; ++j)
                acc[j] = fmaf(zc, emb[(kbase + j) * C_DIM + c], acc[j]);
        }
    }

    float best = 3.402823466e38f;
    int   bidx = 0;
    #pragma unroll
    for (int j = 0; j < TK; ++j) {
        const float d = (znorm - 2.0f * acc[j]) + enorm[kbase + j];
        if (d < best) { best = d; bidx = kbase + j; }   // strict < = first-min
    }

    sh_best[t] = best;   // t == kq*BLKP + lane
    sh_bidx[t] = bidx;
    __syncthreads();

    if (t < BLKP) {   // wave 0: thread t owns position p = t
        const int p = t;
        float bb = sh_best[p];
        int   bi = sh_bidx[p];
        #pragma unroll
        for (int q = 1; q < NQ; ++q) {
            const float bq = sh_best[q * BLKP + p];
            const int   iq = sh_bidx[q * BLKP + p];
            if (bq < bb) { bb = bq; bi = iq; }  // strict <: lower octant wins ties
        }
        const int fin = bi;
        const int pos = blk * BLKP + p;
        __builtin_nontemporal_store((float)fin, &out[IDX_OFF + pos]);

        // Epilogue: q = z + (e - z), loss += (e - z)^2. z from LDS (bit-copy),
        // e from row-major emb via float4 (bit-equal to embT), ascending-c
        // 128-term chain identical to the absmax-0 lineage.
        float lsum = 0.f;
        float* qp = out + zoff + p;
        const float4* __restrict__ er =
            reinterpret_cast<const float4*>(emb + fin * C_DIM);
        #pragma unroll 4
        for (int j = 0; j < C_DIM / 4; ++j) {
            const float4 ev = er[j];
            const int c0 = j * 4;
            const float z0 = zlds[(c0 + 0) * BLKP + p];
            const float z1 = zlds[(c0 + 1) * BLKP + p];
            const float z2 = zlds[(c0 + 2) * BLKP + p];
            const float z3 = zlds[(c0 + 3) * BLKP + p];
            const float d0 = ev.x - z0, d1 = ev.y - z1;
            const float d2 = ev.z - z2, d3 = ev.w - z3;
            lsum = fmaf(d0, d0, lsum);
            lsum = fmaf(d1, d1, lsum);
            lsum = fmaf(d2, d2, lsum);
            lsum = fmaf(d3, d3, lsum);
            __builtin_nontemporal_store(z0 + d0, &qp[(size_t)(c0 + 0) * HW]);
            __builtin_nontemporal_store(z1 + d1, &qp[(size_t)(c0 + 1) * HW]);
            __builtin_nontemporal_store(z2 + d2, &qp[(size_t)(c0 + 2) * HW]);
            __builtin_nontemporal_store(z3 + d3, &qp[(size_t)(c0 + 3) * HW]);
        }

        // Wave-level reduction, one atomic per block (same 4096 partials).
        #pragma unroll
        for (int off = 32; off > 0; off >>= 1)
            lsum += __shfl_down(lsum, off, 64);
        if (p == 0) atomicAdd(loss_acc, lsum);
    }
}

// ---------------------------------------------------------------------------
// Kernel 2: finalize the two scalar losses.
// ---------------------------------------------------------------------------
__global__ void vq_finalize(const float* __restrict__ loss_acc,
                            float* __restrict__ out_losses) {
    float S = loss_acc[0];
    float mean = S / (float)Q_ELEMS;
    out_losses[0] = 0.25f * mean;  // commitment_loss
    out_losses[1] = mean;          // codebook_loss
}

extern "C" void kernel_launch(void* const* d_in, const int* in_sizes, int n_in,
                              void* d_out, int out_size, void* d_ws, size_t ws_size,
                              hipStream_t stream) {
    const float* z   = (const float*)d_in[0];
    const float* emb = (const float*)d_in[1];
    float* out = (float*)d_out;
    float* ws  = (float*)d_ws;

    int use_embT = (ws_size >= (size_t)WS_NEED_FULL) ? 1 : 0;

    vq_transpose<<<C_DIM, K_EMB, 0, stream>>>(emb, ws, use_embT);
    vq_enorm<<<1, K_EMB, 0, stream>>>(emb, ws);
    if (use_embT)
        vq_main<1><<<NPOS / BLKP, NTHR, 0, stream>>>(z, emb, ws, out, ws + WS_ACC);
    else
        vq_main<0><<<NPOS / BLKP, NTHR, 0, stream>>>(z, emb, ws, out, ws + WS_ACC);
    vq_finalize<<<1, 1, 0, stream>>>(ws + WS_ACC, out + LOSS_OFF);
}